// Round 1
// baseline (687.512 us; speedup 1.0000x reference)
//
#include <hip/hip_runtime.h>

#define NN 50000
#define NE 800000

// ---------------------------------------------------------------------------
// k_lin12: a = x@W1 + b1 ; skip = x@W2 + b2   (x:[NN,128], W:[128,64])
// block=256 (4 waves), 32 rows/block; wave g handles rows g*8..g*8+7.
// LDS x-tile 16KB; weight reads coalesced, L1/L2-cached across blocks.
// ---------------------------------------------------------------------------
__global__ __launch_bounds__(256) void k_lin12(
    const float* __restrict__ x,
    const float* __restrict__ w1, const float* __restrict__ b1,
    const float* __restrict__ w2, const float* __restrict__ b2,
    float* __restrict__ a, float* __restrict__ skip)
{
    __shared__ float xs[32 * 128];
    const int tid = threadIdx.x;
    const int row0 = blockIdx.x * 32;
    for (int i = tid; i < 32 * 128; i += 256) {
        const int gr = row0 + (i >> 7);
        xs[i] = (gr < NN) ? x[gr * 128 + (i & 127)] : 0.f;
    }
    __syncthreads();

    const int col = tid & 63;
    const int g = tid >> 6;
    float acc1[8], acc2[8];
#pragma unroll
    for (int r = 0; r < 8; ++r) { acc1[r] = 0.f; acc2[r] = 0.f; }

    for (int k = 0; k < 128; ++k) {
        const float wv1 = w1[k * 64 + col];
        const float wv2 = w2[k * 64 + col];
#pragma unroll
        for (int r = 0; r < 8; ++r) {
            const float xv = xs[(g * 8 + r) * 128 + k];  // wave-broadcast
            acc1[r] += xv * wv1;
            acc2[r] += xv * wv2;
        }
    }

    const float bv1 = b1[col];
    const float bv2 = b2[col];
#pragma unroll
    for (int r = 0; r < 8; ++r) {
        const int gr = row0 + g * 8 + r;
        if (gr < NN) {
            a[gr * 64 + col]    = acc1[r] + bv1;
            skip[gr * 64 + col] = acc2[r] + bv2;
        }
    }
}

// ---------------------------------------------------------------------------
// k_feat: y = a@W ([NN,64]@[64,256]) and t = a@U ([64,4]) per node.
// block=256, col = tid (covers all 256 y cols), 16 rows/block.
// ---------------------------------------------------------------------------
__global__ __launch_bounds__(256) void k_feat(
    const float* __restrict__ a,
    const float* __restrict__ w, const float* __restrict__ u,
    float* __restrict__ y, float* __restrict__ t)
{
    __shared__ float as[16 * 64];
    const int tid = threadIdx.x;
    const int row0 = blockIdx.x * 16;
    for (int i = tid; i < 16 * 64; i += 256) {
        const int gr = row0 + (i >> 6);
        as[i] = (gr < NN) ? a[gr * 64 + (i & 63)] : 0.f;
    }
    __syncthreads();

    float acc[16];
#pragma unroll
    for (int r = 0; r < 16; ++r) acc[r] = 0.f;

    for (int k = 0; k < 64; ++k) {
        const float wv = w[k * 256 + tid];
#pragma unroll
        for (int r = 0; r < 16; ++r)
            acc[r] += as[r * 64 + k] * wv;   // wave-broadcast LDS read
    }

#pragma unroll
    for (int r = 0; r < 16; ++r) {
        const int gr = row0 + r;
        if (gr < NN) y[(size_t)gr * 256 + tid] = acc[r];
    }

    if (tid < 64) {
        const int r = tid >> 2, h = tid & 3;
        float s = 0.f;
        for (int k = 0; k < 64; ++k) s += as[r * 64 + k] * u[k * 4 + h];
        const int gr = row0 + r;
        if (gr < NN) t[gr * 4 + h] = s;
    }
}

// ---------------------------------------------------------------------------
// k_lin3: out = h@W + b   ([NN,64]@[64,64])
// ---------------------------------------------------------------------------
__global__ __launch_bounds__(256) void k_lin3(
    const float* __restrict__ h,
    const float* __restrict__ w, const float* __restrict__ b,
    float* __restrict__ out)
{
    __shared__ float hs[32 * 64];
    const int tid = threadIdx.x;
    const int row0 = blockIdx.x * 32;
    for (int i = tid; i < 32 * 64; i += 256) {
        const int gr = row0 + (i >> 6);
        hs[i] = (gr < NN) ? h[gr * 64 + (i & 63)] : 0.f;
    }
    __syncthreads();

    const int col = tid & 63;
    const int g = tid >> 6;
    float acc[8];
#pragma unroll
    for (int r = 0; r < 8; ++r) acc[r] = 0.f;

    for (int k = 0; k < 64; ++k) {
        const float wv = w[k * 64 + col];
#pragma unroll
        for (int r = 0; r < 8; ++r)
            acc[r] += hs[(g * 8 + r) * 64 + k] * wv;
    }

    const float bv = b[col];
#pragma unroll
    for (int r = 0; r < 8; ++r) {
        const int gr = row0 + g * 8 + r;
        if (gr < NN) out[gr * 64 + col] = acc[r] + bv;
    }
}

// ---------------------------------------------------------------------------
// k_edge: one wave per edge (grid-stride). lane = output channel.
//   logits l_h = t[src,h]-t[dst,h]+c_h ; q = softmax(l)
//   msg[lane] = sum_h q_h * y[src, h*64+lane]  -> atomicAdd agg[dst,lane]
// ---------------------------------------------------------------------------
__global__ __launch_bounds__(256) void k_edge(
    const int* __restrict__ ei,
    const float* __restrict__ t, const float* __restrict__ y,
    const float* __restrict__ c,
    float* __restrict__ agg, float* __restrict__ cnt, int do_cnt)
{
    const int lane = threadIdx.x & 63;
    const int wave = blockIdx.x * 4 + (threadIdx.x >> 6);
    const int nw = gridDim.x * 4;
    const float c0 = c[0], c1 = c[1], c2 = c[2], c3 = c[3];

    for (int e = wave; e < NE; e += nw) {
        const int src = ei[e];
        const int dst = ei[NE + e];

        const float l0 = t[src * 4 + 0] - t[dst * 4 + 0] + c0;
        const float l1 = t[src * 4 + 1] - t[dst * 4 + 1] + c1;
        const float l2 = t[src * 4 + 2] - t[dst * 4 + 2] + c2;
        const float l3 = t[src * 4 + 3] - t[dst * 4 + 3] + c3;
        const float m = fmaxf(fmaxf(l0, l1), fmaxf(l2, l3));
        const float e0 = __expf(l0 - m);
        const float e1 = __expf(l1 - m);
        const float e2 = __expf(l2 - m);
        const float e3 = __expf(l3 - m);
        const float inv = 1.f / (e0 + e1 + e2 + e3);

        const float* ys = y + (size_t)src * 256;
        const float msg = (e0 * ys[lane] + e1 * ys[64 + lane] +
                           e2 * ys[128 + lane] + e3 * ys[192 + lane]) * inv;

        atomicAdd(agg + dst * 64 + lane, msg);
        if (do_cnt && lane == 0) atomicAdd(cnt + dst, 1.f);
    }
}

// ---------------------------------------------------------------------------
// k_fin: out = relu(agg/clip(cnt,1) + bias + skip)
// ---------------------------------------------------------------------------
__global__ __launch_bounds__(256) void k_fin(
    const float* __restrict__ agg, const float* __restrict__ cnt,
    const float* __restrict__ bias, const float* __restrict__ skip,
    float* __restrict__ out)
{
    const int idx = blockIdx.x * 256 + threadIdx.x;
    if (idx >= NN * 64) return;
    const int i = idx >> 6, col = idx & 63;
    const float v = agg[idx] / fmaxf(cnt[i], 1.f) + bias[col] + skip[idx];
    out[idx] = fmaxf(v, 0.f);
}

extern "C" void kernel_launch(void* const* d_in, const int* in_sizes, int n_in,
                              void* d_out, int out_size, void* d_ws, size_t ws_size,
                              hipStream_t stream) {
    const float* x       = (const float*)d_in[0];
    const int*   ei      = (const int*)d_in[1];   // [2, NE] int32
    const float* lin1_w  = (const float*)d_in[2];
    const float* lin1_b  = (const float*)d_in[3];
    const float* lin2_w  = (const float*)d_in[4];
    const float* lin2_b  = (const float*)d_in[5];
    const float* lin3_w  = (const float*)d_in[6];
    const float* lin3_b  = (const float*)d_in[7];
    const float* conv1_w = (const float*)d_in[8];
    const float* conv1_u = (const float*)d_in[9];
    const float* conv1_c = (const float*)d_in[10];
    const float* conv1_bias = (const float*)d_in[11];
    const float* conv2_w = (const float*)d_in[12];
    const float* conv2_u = (const float*)d_in[13];
    const float* conv2_c = (const float*)d_in[14];
    const float* conv2_bias = (const float*)d_in[15];
    float* out = (float*)d_out;

    // workspace layout (floats): total ~22.65M floats = 90.6 MB
    float* ws   = (float*)d_ws;
    float* agg  = ws;                  // NN*64
    float* cnt  = agg + NN * 64;       // NN
    float* a    = cnt + NN;            // NN*64  (reused as h after layer 1)
    float* skip = a + NN * 64;         // NN*64
    float* tt   = skip + NN * 64;      // NN*4
    float* y    = tt + NN * 4;         // NN*256

    // ---- layer 1 ----
    hipMemsetAsync(agg, 0, (size_t)NN * 64 * sizeof(float), stream);
    hipMemsetAsync(cnt, 0, (size_t)NN * sizeof(float), stream);
    k_lin12<<<(NN + 31) / 32, 256, 0, stream>>>(x, lin1_w, lin1_b, lin2_w, lin2_b, a, skip);
    k_feat<<<(NN + 15) / 16, 256, 0, stream>>>(a, conv1_w, conv1_u, y, tt);
    k_edge<<<2048, 256, 0, stream>>>(ei, tt, y, conv1_c, agg, cnt, 1);
    k_fin<<<(NN * 64 + 255) / 256, 256, 0, stream>>>(agg, cnt, conv1_bias, skip, a); // h -> a

    // ---- layer 2 ----
    hipMemsetAsync(agg, 0, (size_t)NN * 64 * sizeof(float), stream);
    k_feat<<<(NN + 15) / 16, 256, 0, stream>>>(a, conv2_w, conv2_u, y, tt);
    k_lin3<<<(NN + 31) / 32, 256, 0, stream>>>(a, lin3_w, lin3_b, skip);
    k_edge<<<2048, 256, 0, stream>>>(ei, tt, y, conv2_c, agg, cnt, 0);
    k_fin<<<(NN * 64 + 255) / 256, 256, 0, stream>>>(agg, cnt, conv2_bias, skip, out);
}

// Round 2
// 596.006 us; speedup vs baseline: 1.1535x; 1.1535x over previous
//
#include <hip/hip_runtime.h>

#define NN 50000
#define NE 800000

typedef unsigned int uint32;
typedef unsigned short ushort16;

__device__ __forceinline__ ushort16 f2bf(float f) {
    uint32 u = __float_as_uint(f);
    u += 0x7fff + ((u >> 16) & 1);      // round-to-nearest-even
    return (ushort16)(u >> 16);
}
__device__ __forceinline__ float bf2f(ushort16 h) {
    return __uint_as_float(((uint32)h) << 16);
}

// ---------------------------------------------------------------------------
// k_lin12: a = x@W1 + b1 ; skip = x@W2 + b2   (x:[NN,128], W:[128,64])
// ---------------------------------------------------------------------------
__global__ __launch_bounds__(256) void k_lin12(
    const float* __restrict__ x,
    const float* __restrict__ w1, const float* __restrict__ b1,
    const float* __restrict__ w2, const float* __restrict__ b2,
    float* __restrict__ a, float* __restrict__ skip)
{
    __shared__ float xs[32 * 128];
    const int tid = threadIdx.x;
    const int row0 = blockIdx.x * 32;
    for (int i = tid; i < 32 * 128; i += 256) {
        const int gr = row0 + (i >> 7);
        xs[i] = (gr < NN) ? x[gr * 128 + (i & 127)] : 0.f;
    }
    __syncthreads();

    const int col = tid & 63;
    const int g = tid >> 6;
    float acc1[8], acc2[8];
#pragma unroll
    for (int r = 0; r < 8; ++r) { acc1[r] = 0.f; acc2[r] = 0.f; }

    for (int k = 0; k < 128; ++k) {
        const float wv1 = w1[k * 64 + col];
        const float wv2 = w2[k * 64 + col];
#pragma unroll
        for (int r = 0; r < 8; ++r) {
            const float xv = xs[(g * 8 + r) * 128 + k];
            acc1[r] += xv * wv1;
            acc2[r] += xv * wv2;
        }
    }

    const float bv1 = b1[col];
    const float bv2 = b2[col];
#pragma unroll
    for (int r = 0; r < 8; ++r) {
        const int gr = row0 + g * 8 + r;
        if (gr < NN) {
            a[gr * 64 + col]    = acc1[r] + bv1;
            skip[gr * 64 + col] = acc2[r] + bv2;
        }
    }
}

// ---------------------------------------------------------------------------
// k_feat: y = bf16(a@W) ([NN,64]@[64,256]) and t = a@U ([64,4]) per node.
// ---------------------------------------------------------------------------
__global__ __launch_bounds__(256) void k_feat(
    const float* __restrict__ a,
    const float* __restrict__ w, const float* __restrict__ u,
    ushort16* __restrict__ y, float* __restrict__ t)
{
    __shared__ float as[16 * 64];
    const int tid = threadIdx.x;
    const int row0 = blockIdx.x * 16;
    for (int i = tid; i < 16 * 64; i += 256) {
        const int gr = row0 + (i >> 6);
        as[i] = (gr < NN) ? a[gr * 64 + (i & 63)] : 0.f;
    }
    __syncthreads();

    float acc[16];
#pragma unroll
    for (int r = 0; r < 16; ++r) acc[r] = 0.f;

    for (int k = 0; k < 64; ++k) {
        const float wv = w[k * 256 + tid];
#pragma unroll
        for (int r = 0; r < 16; ++r)
            acc[r] += as[r * 64 + k] * wv;
    }

#pragma unroll
    for (int r = 0; r < 16; ++r) {
        const int gr = row0 + r;
        if (gr < NN) y[(size_t)gr * 256 + tid] = f2bf(acc[r]);
    }

    if (tid < 64) {
        const int r = tid >> 2, h = tid & 3;
        float s = 0.f;
        for (int k = 0; k < 64; ++k) s += as[r * 64 + k] * u[k * 4 + h];
        const int gr = row0 + r;
        if (gr < NN) t[gr * 4 + h] = s;
    }
}

// ---------------------------------------------------------------------------
// k_lin3: out = h@W + b   ([NN,64]@[64,64])
// ---------------------------------------------------------------------------
__global__ __launch_bounds__(256) void k_lin3(
    const float* __restrict__ h,
    const float* __restrict__ w, const float* __restrict__ b,
    float* __restrict__ out)
{
    __shared__ float hs[32 * 64];
    const int tid = threadIdx.x;
    const int row0 = blockIdx.x * 32;
    for (int i = tid; i < 32 * 64; i += 256) {
        const int gr = row0 + (i >> 6);
        hs[i] = (gr < NN) ? h[gr * 64 + (i & 63)] : 0.f;
    }
    __syncthreads();

    const int col = tid & 63;
    const int g = tid >> 6;
    float acc[8];
#pragma unroll
    for (int r = 0; r < 8; ++r) acc[r] = 0.f;

    for (int k = 0; k < 64; ++k) {
        const float wv = w[k * 64 + col];
#pragma unroll
        for (int r = 0; r < 8; ++r)
            acc[r] += hs[(g * 8 + r) * 64 + k] * wv;
    }

    const float bv = b[col];
#pragma unroll
    for (int r = 0; r < 8; ++r) {
        const int gr = row0 + g * 8 + r;
        if (gr < NN) out[gr * 64 + col] = acc[r] + bv;
    }
}

// ---------------------------------------------------------------------------
// CSR build: histogram -> single-block scan -> scatter src ids by dst bucket
// ---------------------------------------------------------------------------
__global__ __launch_bounds__(256) void k_hist(const int* __restrict__ ei,
                                              int* __restrict__ deg)
{
    const int i = blockIdx.x * 256 + threadIdx.x;
    if (i < NE) atomicAdd(&deg[ei[NE + i]], 1);
}

__global__ __launch_bounds__(1024) void k_scan(const int* __restrict__ deg,
                                               int* __restrict__ row_ptr,
                                               int* __restrict__ fill)
{
    __shared__ int part[1024];
    const int t = threadIdx.x;
    const int c0 = t * 49;
    const int c1 = min(c0 + 49, NN);
    int s = 0;
    for (int i = c0; i < c1; ++i) s += deg[i];
    part[t] = s;
    __syncthreads();
    for (int off = 1; off < 1024; off <<= 1) {
        const int v = (t >= off) ? part[t - off] : 0;
        __syncthreads();
        part[t] += v;
        __syncthreads();
    }
    int pre = (t == 0) ? 0 : part[t - 1];
    for (int i = c0; i < c1; ++i) {
        row_ptr[i] = pre;
        fill[i] = pre;
        pre += deg[i];
    }
    if (t == 1023) row_ptr[NN] = pre;
}

__global__ __launch_bounds__(256) void k_scatter(const int* __restrict__ ei,
                                                 int* __restrict__ fill,
                                                 int* __restrict__ ssrc)
{
    const int i = blockIdx.x * 256 + threadIdx.x;
    if (i >= NE) return;
    const int dst = ei[NE + i];
    const int pos = atomicAdd(&fill[dst], 1);
    ssrc[pos] = ei[i];
}

// ---------------------------------------------------------------------------
// k_agg: one wave per dst node. lane = output channel. For each incident edge:
// softmax over heads from t, gather bf16 y[src], accumulate in registers.
// Fused epilogue: mean + bias + skip + relu. NO atomics.
// ---------------------------------------------------------------------------
__global__ __launch_bounds__(256) void k_agg(
    const int* __restrict__ row_ptr, const int* __restrict__ ssrc,
    const float* __restrict__ t, const ushort16* __restrict__ y,
    const float* __restrict__ c, const float* __restrict__ bias,
    const float* __restrict__ skip, float* __restrict__ out)
{
    const int lane = threadIdx.x & 63;
    const int node = (blockIdx.x * 256 + threadIdx.x) >> 6;
    if (node >= NN) return;

    const int r0 = row_ptr[node];
    const int r1 = row_ptr[node + 1];
    const float c0 = c[0], c1 = c[1], c2 = c[2], c3 = c[3];
    const float td0 = t[node * 4 + 0], td1 = t[node * 4 + 1];
    const float td2 = t[node * 4 + 2], td3 = t[node * 4 + 3];

    float acc = 0.f;
    int j = r0;
    // 2-edge unrolled body: two independent load chains in flight
    for (; j + 1 < r1; j += 2) {
        const int sA = ssrc[j];
        const int sB = ssrc[j + 1];
        const ushort16* yA = y + (size_t)sA * 256;
        const ushort16* yB = y + (size_t)sB * 256;

        const float a0 = t[sA * 4 + 0] - td0 + c0;
        const float a1 = t[sA * 4 + 1] - td1 + c1;
        const float a2 = t[sA * 4 + 2] - td2 + c2;
        const float a3 = t[sA * 4 + 3] - td3 + c3;
        const float b0 = t[sB * 4 + 0] - td0 + c0;
        const float b1 = t[sB * 4 + 1] - td1 + c1;
        const float b2 = t[sB * 4 + 2] - td2 + c2;
        const float b3 = t[sB * 4 + 3] - td3 + c3;

        const float yA0 = bf2f(yA[lane]);
        const float yA1 = bf2f(yA[64 + lane]);
        const float yA2 = bf2f(yA[128 + lane]);
        const float yA3 = bf2f(yA[192 + lane]);
        const float yB0 = bf2f(yB[lane]);
        const float yB1 = bf2f(yB[64 + lane]);
        const float yB2 = bf2f(yB[128 + lane]);
        const float yB3 = bf2f(yB[192 + lane]);

        const float mA = fmaxf(fmaxf(a0, a1), fmaxf(a2, a3));
        float eA0 = __expf(a0 - mA), eA1 = __expf(a1 - mA);
        float eA2 = __expf(a2 - mA), eA3 = __expf(a3 - mA);
        const float invA = 1.f / (eA0 + eA1 + eA2 + eA3);

        const float mB = fmaxf(fmaxf(b0, b1), fmaxf(b2, b3));
        float eB0 = __expf(b0 - mB), eB1 = __expf(b1 - mB);
        float eB2 = __expf(b2 - mB), eB3 = __expf(b3 - mB);
        const float invB = 1.f / (eB0 + eB1 + eB2 + eB3);

        acc += invA * (eA0 * yA0 + eA1 * yA1 + eA2 * yA2 + eA3 * yA3);
        acc += invB * (eB0 * yB0 + eB1 * yB1 + eB2 * yB2 + eB3 * yB3);
    }
    if (j < r1) {
        const int sA = ssrc[j];
        const ushort16* yA = y + (size_t)sA * 256;
        const float a0 = t[sA * 4 + 0] - td0 + c0;
        const float a1 = t[sA * 4 + 1] - td1 + c1;
        const float a2 = t[sA * 4 + 2] - td2 + c2;
        const float a3 = t[sA * 4 + 3] - td3 + c3;
        const float mA = fmaxf(fmaxf(a0, a1), fmaxf(a2, a3));
        const float e0 = __expf(a0 - mA), e1 = __expf(a1 - mA);
        const float e2 = __expf(a2 - mA), e3 = __expf(a3 - mA);
        const float inv = 1.f / (e0 + e1 + e2 + e3);
        acc += inv * (e0 * bf2f(yA[lane]) + e1 * bf2f(yA[64 + lane]) +
                      e2 * bf2f(yA[128 + lane]) + e3 * bf2f(yA[192 + lane]));
    }

    const float degf = (float)(r1 - r0);
    const float v = acc / fmaxf(degf, 1.f) + bias[lane] + skip[node * 64 + lane];
    out[node * 64 + lane] = fmaxf(v, 0.f);
}

extern "C" void kernel_launch(void* const* d_in, const int* in_sizes, int n_in,
                              void* d_out, int out_size, void* d_ws, size_t ws_size,
                              hipStream_t stream) {
    const float* x       = (const float*)d_in[0];
    const int*   ei      = (const int*)d_in[1];   // [2, NE] int32
    const float* lin1_w  = (const float*)d_in[2];
    const float* lin1_b  = (const float*)d_in[3];
    const float* lin2_w  = (const float*)d_in[4];
    const float* lin2_b  = (const float*)d_in[5];
    const float* lin3_w  = (const float*)d_in[6];
    const float* lin3_b  = (const float*)d_in[7];
    const float* conv1_w = (const float*)d_in[8];
    const float* conv1_u = (const float*)d_in[9];
    const float* conv1_c = (const float*)d_in[10];
    const float* conv1_bias = (const float*)d_in[11];
    const float* conv2_w = (const float*)d_in[12];
    const float* conv2_u = (const float*)d_in[13];
    const float* conv2_c = (const float*)d_in[14];
    const float* conv2_bias = (const float*)d_in[15];
    float* out = (float*)d_out;

    // workspace layout (~56 MB)
    float* ws   = (float*)d_ws;
    float* a    = ws;                        // NN*64 (reused as h)
    float* skip = a + NN * 64;               // NN*64
    float* tt   = skip + NN * 64;            // NN*4
    ushort16* y = (ushort16*)(tt + NN * 4);  // NN*256 bf16
    int* deg    = (int*)(y + (size_t)NN * 256); // NN
    int* row_ptr = deg + NN;                 // NN+1
    int* fill   = row_ptr + NN + 1;          // NN
    int* ssrc   = fill + NN;                 // NE

    // ---- CSR build (edge_index identical for both layers) ----
    hipMemsetAsync(deg, 0, (size_t)NN * sizeof(int), stream);
    k_hist<<<(NE + 255) / 256, 256, 0, stream>>>(ei, deg);
    k_scan<<<1, 1024, 0, stream>>>(deg, row_ptr, fill);
    k_scatter<<<(NE + 255) / 256, 256, 0, stream>>>(ei, fill, ssrc);

    // ---- layer 1 ----
    k_lin12<<<(NN + 31) / 32, 256, 0, stream>>>(x, lin1_w, lin1_b, lin2_w, lin2_b, a, skip);
    k_feat<<<(NN + 15) / 16, 256, 0, stream>>>(a, conv1_w, conv1_u, y, tt);
    k_agg<<<(NN + 3) / 4, 256, 0, stream>>>(row_ptr, ssrc, tt, y, conv1_c, conv1_bias, skip, a);

    // ---- layer 2 ----
    k_feat<<<(NN + 15) / 16, 256, 0, stream>>>(a, conv2_w, conv2_u, y, tt);
    k_lin3<<<(NN + 31) / 32, 256, 0, stream>>>(a, lin3_w, lin3_b, skip);
    k_agg<<<(NN + 3) / 4, 256, 0, stream>>>(row_ptr, ssrc, tt, y, conv2_c, conv2_bias, skip, out);
}

// Round 3
// 488.854 us; speedup vs baseline: 1.4064x; 1.2192x over previous
//
#include <hip/hip_runtime.h>

#define NN 50000
#define NE 800000
#define NB ((NN + 255) / 256)   // 196 scan blocks

typedef unsigned int uint32;
typedef unsigned short ushort16;

__device__ __forceinline__ ushort16 f2bf(float f) {
    uint32 u = __float_as_uint(f);
    u += 0x7fff + ((u >> 16) & 1);      // round-to-nearest-even
    return (ushort16)(u >> 16);
}
__device__ __forceinline__ float bf2f(ushort16 h) {
    return __uint_as_float(((uint32)h) << 16);
}

// ---------------------------------------------------------------------------
// k_lin12: a = x@W1 + b1 ; skip = x@W2 + b2   (x:[NN,128], W:[128,64])
// ---------------------------------------------------------------------------
__global__ __launch_bounds__(256) void k_lin12(
    const float* __restrict__ x,
    const float* __restrict__ w1, const float* __restrict__ b1,
    const float* __restrict__ w2, const float* __restrict__ b2,
    float* __restrict__ a, float* __restrict__ skip)
{
    __shared__ float xs[32 * 128];
    const int tid = threadIdx.x;
    const int row0 = blockIdx.x * 32;
    for (int i = tid; i < 32 * 128; i += 256) {
        const int gr = row0 + (i >> 7);
        xs[i] = (gr < NN) ? x[gr * 128 + (i & 127)] : 0.f;
    }
    __syncthreads();

    const int col = tid & 63;
    const int g = tid >> 6;
    float acc1[8], acc2[8];
#pragma unroll
    for (int r = 0; r < 8; ++r) { acc1[r] = 0.f; acc2[r] = 0.f; }

    for (int k = 0; k < 128; ++k) {
        const float wv1 = w1[k * 64 + col];
        const float wv2 = w2[k * 64 + col];
#pragma unroll
        for (int r = 0; r < 8; ++r) {
            const float xv = xs[(g * 8 + r) * 128 + k];
            acc1[r] += xv * wv1;
            acc2[r] += xv * wv2;
        }
    }

    const float bv1 = b1[col];
    const float bv2 = b2[col];
#pragma unroll
    for (int r = 0; r < 8; ++r) {
        const int gr = row0 + g * 8 + r;
        if (gr < NN) {
            a[gr * 64 + col]    = acc1[r] + bv1;
            skip[gr * 64 + col] = acc2[r] + bv2;
        }
    }
}

// ---------------------------------------------------------------------------
// k_feat: y = bf16(a@W) ([NN,64]@[64,256]) and t = a@U ([64,4]) per node.
// ---------------------------------------------------------------------------
__global__ __launch_bounds__(256) void k_feat(
    const float* __restrict__ a,
    const float* __restrict__ w, const float* __restrict__ u,
    ushort16* __restrict__ y, float* __restrict__ t)
{
    __shared__ float as[16 * 64];
    const int tid = threadIdx.x;
    const int row0 = blockIdx.x * 16;
    for (int i = tid; i < 16 * 64; i += 256) {
        const int gr = row0 + (i >> 6);
        as[i] = (gr < NN) ? a[gr * 64 + (i & 63)] : 0.f;
    }
    __syncthreads();

    float acc[16];
#pragma unroll
    for (int r = 0; r < 16; ++r) acc[r] = 0.f;

    for (int k = 0; k < 64; ++k) {
        const float wv = w[k * 256 + tid];
#pragma unroll
        for (int r = 0; r < 16; ++r)
            acc[r] += as[r * 64 + k] * wv;
    }

#pragma unroll
    for (int r = 0; r < 16; ++r) {
        const int gr = row0 + r;
        if (gr < NN) y[(size_t)gr * 256 + tid] = f2bf(acc[r]);
    }

    if (tid < 64) {
        const int r = tid >> 2, h = tid & 3;
        float s = 0.f;
        for (int k = 0; k < 64; ++k) s += as[r * 64 + k] * u[k * 4 + h];
        const int gr = row0 + r;
        if (gr < NN) t[gr * 4 + h] = s;
    }
}

// ---------------------------------------------------------------------------
// k_lin3: out = h@W + b   ([NN,64]@[64,64])
// ---------------------------------------------------------------------------
__global__ __launch_bounds__(256) void k_lin3(
    const float* __restrict__ h,
    const float* __restrict__ w, const float* __restrict__ b,
    float* __restrict__ out)
{
    __shared__ float hs[32 * 64];
    const int tid = threadIdx.x;
    const int row0 = blockIdx.x * 32;
    for (int i = tid; i < 32 * 64; i += 256) {
        const int gr = row0 + (i >> 6);
        hs[i] = (gr < NN) ? h[gr * 64 + (i & 63)] : 0.f;
    }
    __syncthreads();

    const int col = tid & 63;
    const int g = tid >> 6;
    float acc[8];
#pragma unroll
    for (int r = 0; r < 8; ++r) acc[r] = 0.f;

    for (int k = 0; k < 64; ++k) {
        const float wv = w[k * 64 + col];
#pragma unroll
        for (int r = 0; r < 8; ++r)
            acc[r] += hs[(g * 8 + r) * 64 + k] * wv;
    }

    const float bv = b[col];
#pragma unroll
    for (int r = 0; r < 8; ++r) {
        const int gr = row0 + g * 8 + r;
        if (gr < NN) out[gr * 64 + col] = acc[r] + bv;
    }
}

// ---------------------------------------------------------------------------
// CSR build: histogram -> hierarchical scan (3 kernels) -> scatter
// ---------------------------------------------------------------------------
__global__ __launch_bounds__(256) void k_hist(const int* __restrict__ ei,
                                              int* __restrict__ deg)
{
    const int i = blockIdx.x * 256 + threadIdx.x;
    if (i < NE) atomicAdd(&deg[ei[NE + i]], 1);
}

// level 1: per-block sums of deg (coalesced)
__global__ __launch_bounds__(256) void k_blocksum(const int* __restrict__ deg,
                                                  int* __restrict__ bsum)
{
    __shared__ int red[256];
    const int t = threadIdx.x;
    const int i = blockIdx.x * 256 + t;
    red[t] = (i < NN) ? deg[i] : 0;
    __syncthreads();
    for (int off = 128; off > 0; off >>= 1) {
        if (t < off) red[t] += red[t + off];
        __syncthreads();
    }
    if (t == 0) bsum[blockIdx.x] = red[0];
}

// level 2: single-block exclusive scan of the NB block sums (NB<=256)
__global__ __launch_bounds__(256) void k_scanb(int* __restrict__ bsum)
{
    __shared__ int s[256];
    const int t = threadIdx.x;
    s[t] = (t < NB) ? bsum[t] : 0;
    __syncthreads();
    for (int off = 1; off < 256; off <<= 1) {
        const int v = (t >= off) ? s[t - off] : 0;
        __syncthreads();
        s[t] += v;
        __syncthreads();
    }
    if (t < NB) bsum[t] = (t == 0) ? 0 : s[t - 1];
}

// level 3: in-block exclusive scan + block offset -> row_ptr, fill
__global__ __launch_bounds__(256) void k_scanfin(const int* __restrict__ deg,
                                                 const int* __restrict__ bsum,
                                                 int* __restrict__ row_ptr,
                                                 int* __restrict__ fill)
{
    __shared__ int s[256];
    const int t = threadIdx.x;
    const int i = blockIdx.x * 256 + t;
    const int v = (i < NN) ? deg[i] : 0;
    s[t] = v;
    __syncthreads();
    for (int off = 1; off < 256; off <<= 1) {
        const int u = (t >= off) ? s[t - off] : 0;
        __syncthreads();
        s[t] += u;
        __syncthreads();
    }
    const int excl = s[t] - v + bsum[blockIdx.x];
    if (i < NN) { row_ptr[i] = excl; fill[i] = excl; }
    if (i == NN - 1) row_ptr[NN] = excl + v;
}

__global__ __launch_bounds__(256) void k_scatter(const int* __restrict__ ei,
                                                 int* __restrict__ fill,
                                                 int* __restrict__ ssrc)
{
    const int i = blockIdx.x * 256 + threadIdx.x;
    if (i >= NE) return;
    const int dst = ei[NE + i];
    const int pos = atomicAdd(&fill[dst], 1);
    ssrc[pos] = ei[i];
}

// ---------------------------------------------------------------------------
// k_agg: one wave per dst node. lane = output channel. For each incident edge:
// softmax over heads from t, gather bf16 y[src], accumulate in registers.
// Fused epilogue: mean + bias + skip + relu. NO atomics.
// ---------------------------------------------------------------------------
__global__ __launch_bounds__(256) void k_agg(
    const int* __restrict__ row_ptr, const int* __restrict__ ssrc,
    const float* __restrict__ t, const ushort16* __restrict__ y,
    const float* __restrict__ c, const float* __restrict__ bias,
    const float* __restrict__ skip, float* __restrict__ out)
{
    const int lane = threadIdx.x & 63;
    const int node = (blockIdx.x * 256 + threadIdx.x) >> 6;
    if (node >= NN) return;

    const int r0 = row_ptr[node];
    const int r1 = row_ptr[node + 1];
    const float c0 = c[0], c1 = c[1], c2 = c[2], c3 = c[3];
    const float td0 = t[node * 4 + 0], td1 = t[node * 4 + 1];
    const float td2 = t[node * 4 + 2], td3 = t[node * 4 + 3];

    float acc = 0.f;
    int j = r0;
    for (; j + 1 < r1; j += 2) {
        const int sA = ssrc[j];
        const int sB = ssrc[j + 1];
        const ushort16* yA = y + (size_t)sA * 256;
        const ushort16* yB = y + (size_t)sB * 256;

        const float a0 = t[sA * 4 + 0] - td0 + c0;
        const float a1 = t[sA * 4 + 1] - td1 + c1;
        const float a2 = t[sA * 4 + 2] - td2 + c2;
        const float a3 = t[sA * 4 + 3] - td3 + c3;
        const float b0 = t[sB * 4 + 0] - td0 + c0;
        const float b1 = t[sB * 4 + 1] - td1 + c1;
        const float b2 = t[sB * 4 + 2] - td2 + c2;
        const float b3 = t[sB * 4 + 3] - td3 + c3;

        const float yA0 = bf2f(yA[lane]);
        const float yA1 = bf2f(yA[64 + lane]);
        const float yA2 = bf2f(yA[128 + lane]);
        const float yA3 = bf2f(yA[192 + lane]);
        const float yB0 = bf2f(yB[lane]);
        const float yB1 = bf2f(yB[64 + lane]);
        const float yB2 = bf2f(yB[128 + lane]);
        const float yB3 = bf2f(yB[192 + lane]);

        const float mA = fmaxf(fmaxf(a0, a1), fmaxf(a2, a3));
        float eA0 = __expf(a0 - mA), eA1 = __expf(a1 - mA);
        float eA2 = __expf(a2 - mA), eA3 = __expf(a3 - mA);
        const float invA = 1.f / (eA0 + eA1 + eA2 + eA3);

        const float mB = fmaxf(fmaxf(b0, b1), fmaxf(b2, b3));
        float eB0 = __expf(b0 - mB), eB1 = __expf(b1 - mB);
        float eB2 = __expf(b2 - mB), eB3 = __expf(b3 - mB);
        const float invB = 1.f / (eB0 + eB1 + eB2 + eB3);

        acc += invA * (eA0 * yA0 + eA1 * yA1 + eA2 * yA2 + eA3 * yA3);
        acc += invB * (eB0 * yB0 + eB1 * yB1 + eB2 * yB2 + eB3 * yB3);
    }
    if (j < r1) {
        const int sA = ssrc[j];
        const ushort16* yA = y + (size_t)sA * 256;
        const float a0 = t[sA * 4 + 0] - td0 + c0;
        const float a1 = t[sA * 4 + 1] - td1 + c1;
        const float a2 = t[sA * 4 + 2] - td2 + c2;
        const float a3 = t[sA * 4 + 3] - td3 + c3;
        const float mA = fmaxf(fmaxf(a0, a1), fmaxf(a2, a3));
        const float e0 = __expf(a0 - mA), e1 = __expf(a1 - mA);
        const float e2 = __expf(a2 - mA), e3 = __expf(a3 - mA);
        const float inv = 1.f / (e0 + e1 + e2 + e3);
        acc += inv * (e0 * bf2f(yA[lane]) + e1 * bf2f(yA[64 + lane]) +
                      e2 * bf2f(yA[128 + lane]) + e3 * bf2f(yA[192 + lane]));
    }

    const float degf = (float)(r1 - r0);
    const float v = acc / fmaxf(degf, 1.f) + bias[lane] + skip[node * 64 + lane];
    out[node * 64 + lane] = fmaxf(v, 0.f);
}

extern "C" void kernel_launch(void* const* d_in, const int* in_sizes, int n_in,
                              void* d_out, int out_size, void* d_ws, size_t ws_size,
                              hipStream_t stream) {
    const float* x       = (const float*)d_in[0];
    const int*   ei      = (const int*)d_in[1];   // [2, NE] int32
    const float* lin1_w  = (const float*)d_in[2];
    const float* lin1_b  = (const float*)d_in[3];
    const float* lin2_w  = (const float*)d_in[4];
    const float* lin2_b  = (const float*)d_in[5];
    const float* lin3_w  = (const float*)d_in[6];
    const float* lin3_b  = (const float*)d_in[7];
    const float* conv1_w = (const float*)d_in[8];
    const float* conv1_u = (const float*)d_in[9];
    const float* conv1_c = (const float*)d_in[10];
    const float* conv1_bias = (const float*)d_in[11];
    const float* conv2_w = (const float*)d_in[12];
    const float* conv2_u = (const float*)d_in[13];
    const float* conv2_c = (const float*)d_in[14];
    const float* conv2_bias = (const float*)d_in[15];
    float* out = (float*)d_out;

    // workspace layout (~56 MB)
    float* ws   = (float*)d_ws;
    float* a    = ws;                        // NN*64 (reused as h)
    float* skip = a + NN * 64;               // NN*64
    float* tt   = skip + NN * 64;            // NN*4
    ushort16* y = (ushort16*)(tt + NN * 4);  // NN*256 bf16
    int* deg    = (int*)(y + (size_t)NN * 256); // NN
    int* row_ptr = deg + NN;                 // NN+1
    int* fill   = row_ptr + NN + 1;          // NN
    int* bsum   = fill + NN;                 // NB
    int* ssrc   = bsum + NB;                 // NE

    // ---- CSR build (edge_index identical for both layers) ----
    hipMemsetAsync(deg, 0, (size_t)NN * sizeof(int), stream);
    k_hist<<<(NE + 255) / 256, 256, 0, stream>>>(ei, deg);
    k_blocksum<<<NB, 256, 0, stream>>>(deg, bsum);
    k_scanb<<<1, 256, 0, stream>>>(bsum);
    k_scanfin<<<NB, 256, 0, stream>>>(deg, bsum, row_ptr, fill);
    k_scatter<<<(NE + 255) / 256, 256, 0, stream>>>(ei, fill, ssrc);

    // ---- layer 1 ----
    k_lin12<<<(NN + 31) / 32, 256, 0, stream>>>(x, lin1_w, lin1_b, lin2_w, lin2_b, a, skip);
    k_feat<<<(NN + 15) / 16, 256, 0, stream>>>(a, conv1_w, conv1_u, y, tt);
    k_agg<<<(NN + 3) / 4, 256, 0, stream>>>(row_ptr, ssrc, tt, y, conv1_c, conv1_bias, skip, a);

    // ---- layer 2 ----
    k_feat<<<(NN + 15) / 16, 256, 0, stream>>>(a, conv2_w, conv2_u, y, tt);
    k_lin3<<<(NN + 31) / 32, 256, 0, stream>>>(a, lin3_w, lin3_b, skip);
    k_agg<<<(NN + 3) / 4, 256, 0, stream>>>(row_ptr, ssrc, tt, y, conv2_c, conv2_bias, skip, out);
}